// Round 1
// baseline (243.446 us; speedup 1.0000x reference)
//
#include <hip/hip_runtime.h>
#include <hip/hip_bf16.h>

#define DD 256
#define NN 204800
#define SB 4096   // number of segments (B)
#define KT 64
#define NT 64

typedef __attribute__((ext_vector_type(8))) short bf16x8;
typedef __attribute__((ext_vector_type(4))) float f32x4;

__device__ __forceinline__ unsigned short f2bf(float x) {
    union { float f; unsigned u; } v; v.f = x;
    unsigned r = v.u + 0x7FFF + ((v.u >> 16) & 1);
    return (unsigned short)(r >> 16);
}

// ---------------- K1: segment offsets via binary search over sorted seg ids ----
__global__ void k_segstart(const int* __restrict__ seg, int* __restrict__ seg_start) {
    int b = blockIdx.x * blockDim.x + threadIdx.x;
    if (b > SB) return;
    int lo = 0, hi = NN;
    while (lo < hi) {
        int mid = (lo + hi) >> 1;
        if (seg[mid] < b) lo = mid + 1; else hi = mid;
    }
    seg_start[b] = lo;
}

// ---------------- K1b: convert Wu to bf16 once --------------------------------
__global__ void k_cvt_wu(const float* __restrict__ Wu, unsigned short* __restrict__ wub) {
    int i = blockIdx.x * 256 + threadIdx.x;
    wub[i] = f2bf(Wu[i]);
}

// ---------------- K2: anchor = segment mean -> out[:, D:2D] -------------------
__global__ void k_anchor(const float* __restrict__ ifeat, const int* __restrict__ seg_start,
                         float* __restrict__ out) {
    int b = blockIdx.x;
    int d = threadIdx.x;
    int s0 = seg_start[b], s1 = seg_start[b + 1];
    float acc = 0.f;
    for (int i = s0; i < s1; ++i) acc += ifeat[i * DD + d];
    float cnt = (float)(s1 - s0);
    out[b * 2 * DD + DD + d] = acc / fmaxf(cnt, 1.f);
}

// ---------------- K3: feat_v = anchor @ Wv^T + bv -----------------------------
__global__ void k_featv(const float* __restrict__ out, const float* __restrict__ Wv,
                        const float* __restrict__ bv, float* __restrict__ feat_v) {
    int b0 = blockIdx.x * 16;
    int d = threadIdx.x;
    __shared__ float anc[16][DD];
    #pragma unroll
    for (int r = 0; r < 16; ++r) anc[r][d] = out[(b0 + r) * 2 * DD + DD + d];
    __syncthreads();
    float acc[16];
    float bvd = bv[d];
    #pragma unroll
    for (int r = 0; r < 16; ++r) acc[r] = bvd;
    for (int k = 0; k < DD; k += 4) {
        float4 wv4 = *(const float4*)&Wv[d * DD + k];
        #pragma unroll
        for (int r = 0; r < 16; ++r) {
            acc[r] += wv4.x * anc[r][k] + wv4.y * anc[r][k + 1]
                    + wv4.z * anc[r][k + 2] + wv4.w * anc[r][k + 3];
        }
    }
    #pragma unroll
    for (int r = 0; r < 16; ++r) feat_v[(b0 + r) * DD + d] = acc[r];
}

// ---------------- K4: e[i] = sigmoid(ifeat@Wu^T + feat_v[seg]) . we -----------
__global__ __launch_bounds__(256, 3) void k_e(const float* __restrict__ ifeat,
                                              const unsigned short* __restrict__ wub,
                                              const float* __restrict__ feat_v,
                                              const float* __restrict__ we,
                                              const int* __restrict__ seg,
                                              float* __restrict__ e_ws) {
    __shared__ unsigned short xl[NT][72];   // 64 rows x 64 k (bf16), pad to 72
    __shared__ unsigned short wl[DD][72];   // 256 d-rows x 64 k (bf16)
    __shared__ float we_l[DD];
    int t = threadIdx.x;
    int n0 = blockIdx.x * NT;
    we_l[t] = we[t];
    f32x4 acc[16];
    #pragma unroll
    for (int i = 0; i < 16; ++i) acc[i] = (f32x4){0.f, 0.f, 0.f, 0.f};

    int w = t >> 6, lane = t & 63;
    int ar = w * 16 + (lane & 15);
    int ko = (lane >> 4) * 8;

    for (int kt = 0; kt < 4; ++kt) {
        // stage ifeat tile 64x64 f32 -> bf16
        #pragma unroll
        for (int i = 0; i < 4; ++i) {
            int f = i * 256 + t;
            int r = f >> 4, c4 = (f & 15) * 4;
            float4 v = *(const float4*)&ifeat[(size_t)(n0 + r) * DD + kt * KT + c4];
            unsigned short* p = &xl[r][c4];
            p[0] = f2bf(v.x); p[1] = f2bf(v.y); p[2] = f2bf(v.z); p[3] = f2bf(v.w);
        }
        // stage Wu tile 256x64 bf16 (pre-converted)
        #pragma unroll
        for (int i = 0; i < 8; ++i) {
            int f = i * 256 + t;
            int r = f >> 3, c8 = (f & 7) * 8;
            *(uint4*)&wl[r][c8] = *(const uint4*)&wub[r * DD + kt * KT + c8];
        }
        __syncthreads();
        bf16x8 a0 = *(const bf16x8*)&xl[ar][ko];
        bf16x8 a1 = *(const bf16x8*)&xl[ar][32 + ko];
        #pragma unroll
        for (int dt = 0; dt < 16; ++dt) {
            int br = dt * 16 + (lane & 15);
            bf16x8 b0 = *(const bf16x8*)&wl[br][ko];
            bf16x8 b1 = *(const bf16x8*)&wl[br][32 + ko];
            acc[dt] = __builtin_amdgcn_mfma_f32_16x16x32_bf16(a0, b0, acc[dt], 0, 0, 0);
            acc[dt] = __builtin_amdgcn_mfma_f32_16x16x32_bf16(a1, b1, acc[dt], 0, 0, 0);
        }
        __syncthreads();
    }

    // epilogue: e[node] = sum_d sigmoid(U + feat_v[seg][d]) * we[d]
    int g = lane >> 4, col = lane & 15;
    float partial[4] = {0.f, 0.f, 0.f, 0.f};
    int sg[4];
    #pragma unroll
    for (int e = 0; e < 4; ++e) sg[e] = seg[n0 + w * 16 + g * 4 + e];
    #pragma unroll
    for (int dt = 0; dt < 16; ++dt) {
        int d = dt * 16 + col;
        float wd = we_l[d];
        #pragma unroll
        for (int e = 0; e < 4; ++e) {
            float u = acc[dt][e] + feat_v[sg[e] * DD + d];
            partial[e] += wd / (1.f + __expf(-u));
        }
    }
    #pragma unroll
    for (int e = 0; e < 4; ++e) {
        float p = partial[e];
        p += __shfl_xor(p, 1, 64);
        p += __shfl_xor(p, 2, 64);
        p += __shfl_xor(p, 4, 64);
        p += __shfl_xor(p, 8, 64);
        if (col == 0) e_ws[n0 + w * 16 + g * 4 + e] = p;
    }
}

// ---------------- K5: segment softmax + weighted sum -> out[:, 0:D] -----------
__global__ void k_rst(const float* __restrict__ ifeat, float* __restrict__ e_ws,
                      const int* __restrict__ seg_start, float* __restrict__ out) {
    int b = blockIdx.x;
    int t = threadIdx.x;
    int s0 = seg_start[b], s1 = seg_start[b + 1];
    int cnt = s1 - s0;
    if (cnt == 0) { out[b * 2 * DD + t] = 0.f; return; }
    __shared__ float red[4];
    __shared__ float bm, bd;
    int wv = t >> 6;
    // max
    float m = -1e30f;
    for (int i = s0 + t; i < s1; i += 256) m = fmaxf(m, e_ws[i]);
    #pragma unroll
    for (int off = 1; off < 64; off <<= 1) m = fmaxf(m, __shfl_xor(m, off, 64));
    if ((t & 63) == 0) red[wv] = m;
    __syncthreads();
    if (t == 0) bm = fmaxf(fmaxf(red[0], red[1]), fmaxf(red[2], red[3]));
    __syncthreads();
    m = bm;
    // exp + sum (ex written back to e_ws, each index owned by one thread)
    float s = 0.f;
    for (int i = s0 + t; i < s1; i += 256) {
        float ex = expf(e_ws[i] - m);
        e_ws[i] = ex;
        s += ex;
    }
    #pragma unroll
    for (int off = 1; off < 64; off <<= 1) s += __shfl_xor(s, off, 64);
    if ((t & 63) == 0) red[wv] = s;
    __syncthreads();
    if (t == 0) bd = red[0] + red[1] + red[2] + red[3];
    __syncthreads();
    float inv = 1.f / bd;
    // weighted sum over segment rows, d = t
    float acc = 0.f;
    for (int i = s0; i < s1; ++i) acc += e_ws[i] * ifeat[(size_t)i * DD + t];
    out[b * 2 * DD + t] = acc * inv;
}

extern "C" void kernel_launch(void* const* d_in, const int* in_sizes, int n_in,
                              void* d_out, int out_size, void* d_ws, size_t ws_size,
                              hipStream_t stream) {
    const float* ifeat = (const float*)d_in[0];
    const float* Wu    = (const float*)d_in[1];
    const float* Wv    = (const float*)d_in[2];
    const float* bv    = (const float*)d_in[3];
    const float* we    = (const float*)d_in[4];
    const int*   seg   = (const int*)d_in[5];
    float* out = (float*)d_out;

    char* ws = (char*)d_ws;
    int*   seg_start = (int*)ws;                                   // (SB+1)*4 -> pad 32KB
    float* e_ws      = (float*)(ws + 32768);                       // NN*4 = 819200
    float* feat_v    = (float*)(ws + 32768 + 819200);              // SB*DD*4 = 4194304
    unsigned short* wub = (unsigned short*)(ws + 32768 + 819200 + 4194304); // 128KB

    k_segstart<<<dim3((SB + 1 + 255) / 256), dim3(256), 0, stream>>>(seg, seg_start);
    k_cvt_wu<<<dim3(DD * DD / 256), dim3(256), 0, stream>>>(Wu, wub);
    k_anchor<<<dim3(SB), dim3(256), 0, stream>>>(ifeat, seg_start, out);
    k_featv<<<dim3(SB / 16), dim3(256), 0, stream>>>(out, Wv, bv, feat_v);
    k_e<<<dim3(NN / NT), dim3(256), 0, stream>>>(ifeat, wub, feat_v, we, seg, e_ws);
    k_rst<<<dim3(SB), dim3(256), 0, stream>>>(ifeat, e_ws, seg_start, out);
}